// Round 1
// baseline (277.299 us; speedup 1.0000x reference)
//
#include <hip/hip_runtime.h>
#include <math.h>

// Algebraic collapse: out depends on h = X@We + be only through h@Wc and h@Wf.
//   logits[:, 0:20]  = X @ (We@Wc) + (be@Wc + bc)
//   logits[:, 20:40] = X @ (We@Wf) + (be@Wf + bf)
// K0: zero Weff, fold bias2 = [be@Wc + bc | be@Wf + bf]
// K1: Weff = We @ [Wc|Wf]  (skinny GEMM template, 8-way block-K atomic split;
//     col-group waves read Wc / Wf DIRECTLY -> no packed Wcat needed)
// K2: out  = epilogue(X @ Weff + bias2)   (fused softmax+threshold)
//
// This revision vs. previous: packed fp32 math (v_pk_fma_f32 -> 2 FMA/instr,
// halves VALU issue), row-major stride-132 LDS X-tile with b128 store+read
// (12 LDS instrs/chunk-thread -> 3, conflict-free by quad-spread), 128-k
// chunks (half the barriers), full-GPU K1, vectorized epilogue.

typedef float v2f __attribute__((ext_vector_type(2)));
typedef float v4f __attribute__((ext_vector_type(4)));

#define KD    2048
#define NCLS  20
#define NC2   40
#define SMARG 0.31f

// ws layout (floats): Weff[2048*40] then bias2[40]  -> 328 KB total
#define WEFF_OFF 0
#define BIAS_OFF 81920

#define CHUNK   128
#define XS_STR  132                 // 128+4 pad: quad index (33*lane+q)%8 uniform
#define XS_BUF  (64 * XS_STR)       // 8448 floats per buffer
#define HACC_STR 44                 // 16B-aligned rows, 11*row+q quad-spread
#define HACC_WS  (64 * HACC_STR)    // 2816
#define SMEM_FLOATS 22528           // max(2*XS_BUF=16896, 8*HACC_WS=22528) = 90 KB

static __device__ __forceinline__ v2f fma2(v2f a, v2f b, v2f c) {
#if __has_builtin(__builtin_elementwise_fma)
    return __builtin_elementwise_fma(a, b, c);   // -> v_pk_fma_f32
#else
    v2f r; r[0] = fmaf(a[0], b[0], c[0]); r[1] = fmaf(a[1], b[1], c[1]); return r;
#endif
}

// ---------------- K0: zero Weff, fold bias2 --------------------------------
__global__ __launch_bounds__(256)
void k0_prep(const float* __restrict__ Wc, const float* __restrict__ bc,
             const float* __restrict__ Wf, const float* __restrict__ bf,
             const float* __restrict__ be, float* __restrict__ ws)
{
    const int b = blockIdx.x;
    const int t = threadIdx.x;
    if (b < 80) {                                   // zero Weff: 80*256*4 = 81920
        v4f z = {0.f, 0.f, 0.f, 0.f};
        *(v4f*)&ws[WEFF_OFF + 4 * (b * 256 + t)] = z;
    } else {                                        // bias2[col], col = b-80
        const int col = b - 80;
        const float* Wp = (col < NCLS) ? Wc : Wf;
        const int cc = (col < NCLS) ? col : col - NCLS;
        float p = 0.f;
        for (int n = t; n < KD; n += 256)
            p = fmaf(be[n], Wp[n * NCLS + cc], p);
        __shared__ float red[256];
        red[t] = p;
        __syncthreads();
        for (int s = 128; s > 0; s >>= 1) {
            if (t < s) red[t] += red[t + s];
            __syncthreads();
        }
        if (t == 0)
            ws[BIAS_OFF + col] = red[0] + ((col < NCLS) ? bc[cc] : bf[cc]);
    }
}

// ---------------- skinny GEMM core: C[M,40] (+=) A[M,2048] @ B[2048,40] ----
// Block: 1024 thr = 16 waves = 2 col-groups x 8 in-chunk K-splits over ONE
// shared 64-row x 128-k LDS tile (double-buffered, row-major stride 132,
// ds_write_b128 / ds_read_b128 both conflict-free). B is read via wave-uniform
// addresses (readfirstlane-forced wave id) -> scalar s_loads, consumed as
// float2 pairs by v_pk_fma_f32 (2 FMA / VALU instr). In-block LDS reduce over
// the 8 K-splits.  BSTR: B row stride (20 = direct Wc/Wf, 40 = Weff).
template<int NCHUNKS, int BSTR, bool FUSED>
__global__ __launch_bounds__(1024)
void skinny_gemm(const float* __restrict__ A,
                 const float* __restrict__ B0,      // col-group 0 base
                 const float* __restrict__ B1,      // col-group 1 base
                 float* __restrict__ Cacc,          // !FUSED: atomic target
                 const float* __restrict__ bias2,   // FUSED
                 float* __restrict__ outp)          // FUSED
{
    __shared__ __align__(16) float smem[SMEM_FLOATS];
    const int tid  = threadIdx.x;
    const int lane = tid & 63;
    const int wu   = __builtin_amdgcn_readfirstlane(tid >> 6);  // wave id 0..15
    const int cgu  = wu & 1;            // col-group: 20 cols
    const int ksu  = wu >> 1;           // in-chunk k-split 0..7 (16 k each)

    int m0, kbase;
    if (FUSED) { m0 = blockIdx.x * 64;        kbase = 0; }
    else       { m0 = (blockIdx.x >> 3) * 64; kbase = (blockIdx.x & 7) * (NCHUNKS * CHUNK); }

    const int lrow = tid >> 4;          // 0..63 (4 rows/wave -> 256B segments)
    const int lkq  = tid & 15;          // 16 float4 per 64-k half-row
    const float* aptr  = A + (size_t)(m0 + lrow) * KD + kbase + 4 * lkq;
    const float* bbase = (cgu ? B1 : B0) + (size_t)(kbase + ksu * (CHUNK / 8)) * BSTR;

    v2f acc[10];
    #pragma unroll
    for (int j = 0; j < 10; ++j) acc[j] = (v2f){0.f, 0.f};

    // prologue: stage chunk 0 into buf 0 (row-major, 2 x b128 per thread)
    {
        v4f v0 = *(const v4f*)(aptr);
        v4f v1 = *(const v4f*)(aptr + 64);
        float* xb = smem + lrow * XS_STR;
        *(v4f*)(xb + 4 * lkq)      = v0;
        *(v4f*)(xb + 64 + 4 * lkq) = v1;
    }
    __syncthreads();

    for (int c = 0; c < NCHUNKS; ++c) {
        const int buf = c & 1;
        v4f p0, p1;
        if (c + 1 < NCHUNKS) {                      // prefetch next chunk
            p0 = *(const v4f*)(aptr + (c + 1) * CHUNK);
            p1 = *(const v4f*)(aptr + (c + 1) * CHUNK + 64);
        }

        const float* xs   = smem + buf * XS_BUF + lane * XS_STR + ksu * (CHUNK / 8);
        const float* brow = bbase + (size_t)c * (CHUNK * BSTR);
        #pragma unroll 2
        for (int q = 0; q < 4; ++q) {               // 4 x ds_read_b128 per chunk
            v4f xv = *(const v4f*)(xs + 4 * q);
            #pragma unroll
            for (int i = 0; i < 4; ++i) {
                v2f xx = { xv[i], xv[i] };
                const float* br = brow + (4 * q + i) * BSTR;
                #pragma unroll
                for (int j = 0; j < 10; ++j)        // 10 x v_pk_fma_f32
                    acc[j] = fma2(xx, *(const v2f*)(br + 2 * j), acc[j]);
            }
        }

        if (c + 1 < NCHUNKS) {
            float* xb = smem + (buf ^ 1) * XS_BUF + lrow * XS_STR;
            *(v4f*)(xb + 4 * lkq)      = p0;
            *(v4f*)(xb + 64 + 4 * lkq) = p1;
        }
        __syncthreads();
    }

    // in-block reduce over the 8 k-splits: Hacc[ks][row][c] (aliases Xs, dead)
    float* H = smem;
    {
        float* Hw = H + ksu * HACC_WS + lane * HACC_STR + 20 * cgu;
        #pragma unroll
        for (int j = 0; j < 10; ++j)
            *(v2f*)(Hw + 2 * j) = acc[j];           // ds_write_b64, ~2-way (free)
    }
    __syncthreads();

    if (FUSED) {
        if (tid < 64) {
            v4f l4[10];
            #pragma unroll
            for (int j = 0; j < 10; ++j) {
                v4f s = *(const v4f*)(H + tid * HACC_STR + 4 * j);
                #pragma unroll
                for (int ks = 1; ks < 8; ++ks)
                    s += *(const v4f*)(H + ks * HACC_WS + tid * HACC_STR + 4 * j);
                l4[j] = s + *(const v4f*)(bias2 + 4 * j);
            }
            // classifier head: cols 0..19 = l4[0..4]
            float mC = l4[0][0];
            #pragma unroll
            for (int j = 0; j < 5; ++j) {
                #pragma unroll
                for (int i = 0; i < 4; ++i) mC = fmaxf(mC, l4[j][i]);
            }
            float e[20];
            float sC = 0.f;
            #pragma unroll
            for (int j = 0; j < 5; ++j) {
                #pragma unroll
                for (int i = 0; i < 4; ++i) {
                    float ev = expf(l4[j][i] - mC);
                    e[4 * j + i] = ev;
                    sC += ev;
                }
            }
            // flow head: cols 20..39 = l4[5..9]
            float mF = l4[5][0], mnF = l4[5][0];
            #pragma unroll
            for (int j = 5; j < 10; ++j) {
                #pragma unroll
                for (int i = 0; i < 4; ++i) {
                    float vv = l4[j][i];
                    mF = fmaxf(mF, vv);
                    mnF = fminf(mnF, vv);
                }
            }
            float sF = 0.f;
            #pragma unroll
            for (int j = 5; j < 10; ++j) {
                #pragma unroll
                for (int i = 0; i < 4; ++i) sF += expf(l4[j][i] - mF);
            }
            float pred  = 1.f / sC;                 // max softmax == exp(0)/sum
            float tau   = expf(mnF - mF) / sF;      // min softmax of flow head
            float scale = (pred >= tau + SMARG) ? pred : 0.f;
            float* op = outp + (size_t)(m0 + tid) * NCLS;
            #pragma unroll
            for (int j = 0; j < 5; ++j) {
                v4f o;
                #pragma unroll
                for (int i = 0; i < 4; ++i) o[i] = e[4 * j + i] * scale;
                *(v4f*)(op + 4 * j) = o;            // global_store_dwordx4
            }
        }
    } else {
        for (int idx = tid; idx < 64 * NC2; idx += 1024) {
            int row = idx / NC2, cc = idx % NC2;
            float s = 0.f;
            #pragma unroll
            for (int ks = 0; ks < 8; ++ks)
                s += H[ks * HACC_WS + row * HACC_STR + cc];
            atomicAdd(Cacc + (size_t)(m0 + row) * NC2 + cc, s);
        }
    }
}

extern "C" void kernel_launch(void* const* d_in, const int* in_sizes, int n_in,
                              void* d_out, int out_size, void* d_ws, size_t ws_size,
                              hipStream_t stream) {
    const float* X  = (const float*)d_in[0];
    const float* We = (const float*)d_in[1];
    const float* be = (const float*)d_in[2];
    const float* Wc = (const float*)d_in[3];
    const float* bc = (const float*)d_in[4];
    const float* Wf = (const float*)d_in[5];
    const float* bf = (const float*)d_in[6];
    float* out = (float*)d_out;
    float* ws  = (float*)d_ws;
    (void)in_sizes; (void)n_in; (void)out_size; (void)ws_size;

    // K0: zero Weff + fold bias2
    k0_prep<<<dim3(120), dim3(256), 0, stream>>>(Wc, bc, Wf, bf, be, ws);
    // K1: Weff = We @ [Wc|Wf]  (32 row-groups x 8 block-K-splits = 256 blocks)
    skinny_gemm<2, 20, false><<<dim3(256), dim3(1024), 0, stream>>>(
        We, Wc, Wf, ws + WEFF_OFF, nullptr, nullptr);
    // K2: out = softmax-threshold(X @ Weff + bias2)   (256 blocks x 64 rows)
    skinny_gemm<16, 40, true><<<dim3(256), dim3(1024), 0, stream>>>(
        X, ws + WEFF_OFF, ws + WEFF_OFF + 20, nullptr, ws + BIAS_OFF, out);
}